// Round 8
// baseline (963.467 us; speedup 1.0000x reference)
//
#include <hip/hip_runtime.h>

#define BB 512
#define TT 2048
#define II 8
#define HH 128
#define OO 96

typedef __attribute__((ext_vector_type(8))) short bf16x8;
typedef __attribute__((ext_vector_type(4))) float f32x4;

#define L2E 1.4426950408889634f

__device__ __forceinline__ float fast_rcp(float x) { return __builtin_amdgcn_rcpf(x); }
__device__ __forceinline__ float exp2_fast(float x) {
#if __has_builtin(__builtin_amdgcn_exp2f)
    return __builtin_amdgcn_exp2f(x);
#else
    return __expf(x * 0.6931471805599453f);
#endif
}
__device__ __forceinline__ unsigned short f2bf(float f) {
    unsigned int u = __builtin_bit_cast(unsigned int, f);
    u += 0x7fffu + ((u >> 16) & 1u);   // RNE
    return (unsigned short)(u >> 16);
}
__device__ __forceinline__ float bf2f(unsigned short h) {
    unsigned int u = ((unsigned int)h) << 16;
    return __builtin_bit_cast(float, u);
}
__device__ __forceinline__ float dot8(const float w[8], float4 a, float4 b, float acc) {
    acc = fmaf(w[0], a.x, acc); acc = fmaf(w[1], a.y, acc);
    acc = fmaf(w[2], a.z, acc); acc = fmaf(w[3], a.w, acc);
    acc = fmaf(w[4], b.x, acc); acc = fmaf(w[5], b.y, acc);
    acc = fmaf(w[6], b.z, acc); acc = fmaf(w[7], b.w, acc);
    return acc;
}

// Block = 8 waves (512 thr), 2 batch rows, full T scan, grid=256 (1 block/CU).
// r7 structure (role-split r/z sigmoid sharing, exp2-prescale, balanced dots) +
// the HBM-exposure fix:
//  - STEP barrier = s_waitcnt lgkmcnt(0) + s_barrier ONLY (no vmcnt drain).
//    __syncthreads drains vmcnt(0), exposing ~300cyc of HBM latency on the
//    streamed x-loads every other iteration (x lines ~50% HBM-miss at ~900cyc;
//    barrier every ~550cyc caps prefetch slack below that). LDS is the only
//    cross-wave hazard at the step barrier; x-loads never touch LDS.
//  - x prefetched TWO iterations ahead via P/Q register sets, loop manually
//    2x-unrolled (no register copies): ~2300cyc slack >> 900cyc HBM latency.
// Wave w owns j-block [16w,16w+16). MFMA 16x16x32 bf16, K=128 (h only; x-path
// via fp32 dot8). Lanes<32 evaluate r-sigmoid, lanes>=32 z-sigmoid through the
// same instructions (role-split weights); __shfl_xor(.,32) delivers z.
// A-row pattern m: plane=((m>>2)&1)*2+(m&1) over {hi0,lo0,hi1,lo1};
// gate = C[0]+C[1] (bf16 hi/lo split compensation).
// LDS: 2 bufs x 4 planes x 320B, double-buffered, 1 barrier per step.
__global__ __launch_bounds__(512, 2) void gru_kernel(
    const float* __restrict__ x,     // [B, T, I]
    const float* __restrict__ w_ih,  // [3H, I]
    const float* __restrict__ w_hh,  // [3H, H]
    const float* __restrict__ b_ih,  // [3H]
    const float* __restrict__ b_hh,  // [3H]
    const float* __restrict__ fc_w,  // [O, H]
    const float* __restrict__ fc_b,  // [O]
    float* __restrict__ out)         // [B, O]
{
    __shared__ __align__(16) char hbuf[2 * 1280];
    __shared__ __align__(16) float hfin[2][HH];

    const int tid = threadIdx.x;
    const int wv  = tid >> 6;
    const int ln  = tid & 63;
    const int col = ln & 15;       // C col = j within tile
    const int g4  = ln >> 4;       // k-subblock of A/B fragment
    const int b   = g4 & 1;        // this lane's batch row
    const int sel = (ln >= 32);    // 0: finalize r-chain; 1: finalize z-chain
    const int p   = ((ln >> 2) & 1) * 2 + (ln & 1);   // A plane for row=ln&15
    const int j   = 16 * wv + col;
    const int b0  = blockIdx.x * 2;

    // ---- B fragments (w_hh -> bf16, weight-stationary, exp2-prescaled) ----
    auto ldfrag_hh = [&](int grow, int ks, float sc) {
        const float* rowp = w_hh + grow * HH + 32 * ks + g4 * 8;
        float4 u = *(const float4*)(rowp);
        float4 v = *(const float4*)(rowp + 4);
        bf16x8 f;
        f[0] = (short)f2bf(sc * u.x); f[1] = (short)f2bf(sc * u.y);
        f[2] = (short)f2bf(sc * u.z); f[3] = (short)f2bf(sc * u.w);
        f[4] = (short)f2bf(sc * v.x); f[5] = (short)f2bf(sc * v.y);
        f[6] = (short)f2bf(sc * v.z); f[7] = (short)f2bf(sc * v.w);
        return f;
    };

    bf16x8 bR[4], bZ[4], bN[4];
#pragma unroll
    for (int ks = 0; ks < 4; ++ks) {
        bR[ks] = ldfrag_hh(j, ks, -L2E);
        bZ[ks] = ldfrag_hh(HH + j, ks, -L2E);
        bN[ks] = ldfrag_hh(2 * HH + j, ks, 2.0f * L2E);
    }

    // ---- w_ih rows for this lane's role (fp32, exp2-prescaled) ----
    const int rz_row = sel ? (HH + j) : j;
    float wrz[8], wn[8];
    {
        const float* rzp = w_ih + rz_row * II;
        const float* r2p = w_ih + (2 * HH + j) * II;
#pragma unroll
        for (int i = 0; i < 8; ++i) {
            wrz[i] = -L2E * rzp[i];
            wn[i]  = (2.0f * L2E) * r2p[i];
        }
    }

    const float bias_rz2 = -L2E * (b_ih[rz_row] + b_hh[rz_row]);
    const float bias_nh2 = (2.0f * L2E) * b_hh[2 * HH + j];  // inside r*(.), added in tail
    const float bias_nx2 = (2.0f * L2E) * b_ih[2 * HH + j];  // outside, in gx dot

    // ---- zero LDS (h=0 both buffers): 2560 B ----
    for (int i = tid; i < 640; i += 512) ((int*)hbuf)[i] = 0;
    __syncthreads();

    const char* abase = hbuf + p * 320 + g4 * 16;
    char* wbase = hbuf + b * 640 + (j << 1);          // + (1-RBUF)*1280 at use
    const float* xp = x + (size_t)(b0 + b) * TT * II;

    float h0 = 0.f;
    const f32x4 zf = {0.f, 0.f, 0.f, 0.f};

    // ---- prologue: gx for t=0,1; x prefetch for t=2..5 (P/Q sets) ----
    float grz0, gn0, grz1, gn1;
    {
        float4 xa = *(const float4*)(xp);          float4 xb = *(const float4*)(xp + 4);
        float4 xc = *(const float4*)(xp + II);     float4 xd = *(const float4*)(xp + II + 4);
        grz0 = dot8(wrz, xa, xb, bias_rz2);  gn0 = dot8(wn, xa, xb, bias_nx2);
        grz1 = dot8(wrz, xc, xd, bias_rz2);  gn1 = dot8(wn, xc, xd, bias_nx2);
    }
    float4 pa = *(const float4*)(xp + 2 * II), pb = *(const float4*)(xp + 2 * II + 4);
    float4 pc = *(const float4*)(xp + 3 * II), pd = *(const float4*)(xp + 3 * II + 4);
    float4 qa = *(const float4*)(xp + 4 * II), qb = *(const float4*)(xp + 4 * II + 4);
    float4 qc = *(const float4*)(xp + 5 * II), qd = *(const float4*)(xp + 5 * II + 4);
    float grz0n, gn0n, grz1n, gn1n;

#define MFMA_BF16 __builtin_amdgcn_mfma_f32_16x16x32_bf16

// LDS-only step barrier: drains lgkmcnt (my ds_write/ds_read complete) but NOT
// vmcnt — x prefetch loads stay in flight across steps. Memory clobber = compiler
// fence so no DS op migrates across.
#define STEP_BARRIER() \
    asm volatile("s_waitcnt lgkmcnt(0)\n\ts_barrier" ::: "memory");

#define STEP(RBUF, GRZ, GXN, DOTS)                                              \
    {                                                                           \
        const char* ab = abase + (RBUF) * 1280;                                 \
        bf16x8 a0 = *(const bf16x8*)(ab);                                       \
        bf16x8 a1 = *(const bf16x8*)(ab + 64);                                  \
        bf16x8 a2 = *(const bf16x8*)(ab + 128);                                 \
        bf16x8 a3 = *(const bf16x8*)(ab + 192);                                 \
        f32x4 aR = zf, aZ = zf, aN = zf;                                        \
        aR = MFMA_BF16(a0, bR[0], aR, 0, 0, 0);                                 \
        aZ = MFMA_BF16(a0, bZ[0], aZ, 0, 0, 0);                                 \
        aN = MFMA_BF16(a0, bN[0], aN, 0, 0, 0);                                 \
        aR = MFMA_BF16(a1, bR[1], aR, 0, 0, 0);                                 \
        aZ = MFMA_BF16(a1, bZ[1], aZ, 0, 0, 0);                                 \
        aN = MFMA_BF16(a1, bN[1], aN, 0, 0, 0);                                 \
        aR = MFMA_BF16(a2, bR[2], aR, 0, 0, 0);                                 \
        aZ = MFMA_BF16(a2, bZ[2], aZ, 0, 0, 0);                                 \
        aN = MFMA_BF16(a2, bN[2], aN, 0, 0, 0);                                 \
        aR = MFMA_BF16(a3, bR[3], aR, 0, 0, 0);                                 \
        aZ = MFMA_BF16(a3, bZ[3], aZ, 0, 0, 0);                                 \
        aN = MFMA_BF16(a3, bN[3], aN, 0, 0, 0);                                 \
        DOTS                                                                    \
        float c0 = sel ? aZ[0] : aR[0];                                         \
        float c1 = sel ? aZ[1] : aR[1];                                         \
        float grz = c0 + c1 + (GRZ);                                            \
        float s0v = fast_rcp(1.0f + exp2_fast(grz));  /* r (lo) / z (hi) */     \
        float zz  = __shfl_xor(s0v, 32, 64);          /* z on lo-lanes */       \
        float gn  = aN[0] + aN[1] + bias_nh2;                                   \
        float t0  = fast_rcp(1.0f + exp2_fast(fmaf(s0v, gn, (GXN))));           \
        float n0  = fmaf(-2.0f, t0, 1.0f);                                      \
        h0 = fmaf(zz, h0 - n0, n0);                   /* valid on lo-lanes */   \
        if (ln < 32) {                                                          \
            char* w_ = wbase + (1 - (RBUF)) * 1280;                             \
            unsigned short s0 = f2bf(h0);                                       \
            *(unsigned short*)(w_)       = s0;                                  \
            *(unsigned short*)(w_ + 320) = f2bf(h0 - bf2f(s0));                 \
        }                                                                       \
        STEP_BARRIER()                                                          \
    }

    for (int it2 = 0; it2 < TT / 4; ++it2) {
        // ---- body A (steps t=4*it2, 4*it2+1): consume P, reload P (t+6,t+7) ----
        STEP(0, grz0, gn0, {
            grz0n = dot8(wrz, pa, pb, bias_rz2);
            gn0n  = dot8(wn,  pa, pb, bias_nx2);
        })
        STEP(1, grz1, gn1, {
            grz1n = dot8(wrz, pc, pd, bias_rz2);
            gn1n  = dot8(wn,  pc, pd, bias_nx2);
        })
        grz0 = grz0n; gn0 = gn0n; grz1 = grz1n; gn1 = gn1n;
        {
            int t6 = 4 * it2 + 6; if (t6 > TT - 1) t6 = TT - 1;
            int t7 = t6 + 1;      if (t7 > TT - 1) t7 = TT - 1;
            pa = *(const float4*)(xp + (size_t)t6 * II);
            pb = *(const float4*)(xp + (size_t)t6 * II + 4);
            pc = *(const float4*)(xp + (size_t)t7 * II);
            pd = *(const float4*)(xp + (size_t)t7 * II + 4);
        }
        // ---- body B (steps t=4*it2+2, +3): consume Q, reload Q (t+8,t+9) ----
        STEP(0, grz0, gn0, {
            grz0n = dot8(wrz, qa, qb, bias_rz2);
            gn0n  = dot8(wn,  qa, qb, bias_nx2);
        })
        STEP(1, grz1, gn1, {
            grz1n = dot8(wrz, qc, qd, bias_rz2);
            gn1n  = dot8(wn,  qc, qd, bias_nx2);
        })
        grz0 = grz0n; gn0 = gn0n; grz1 = grz1n; gn1 = gn1n;
        {
            int t8 = 4 * it2 + 8; if (t8 > TT - 1) t8 = TT - 1;
            int t9 = t8 + 1;      if (t9 > TT - 1) t9 = TT - 1;
            qa = *(const float4*)(xp + (size_t)t8 * II);
            qb = *(const float4*)(xp + (size_t)t8 * II + 4);
            qc = *(const float4*)(xp + (size_t)t9 * II);
            qd = *(const float4*)(xp + (size_t)t9 * II + 4);
        }
    }
#undef STEP
#undef STEP_BARRIER
#undef MFMA_BF16

    // ---- epilogue FC on fp32 h ----
    if (ln < 32) hfin[b][j] = h0;
    __syncthreads();

    if (tid < 2 * OO) {
        const int bb2 = (tid >= OO) ? 1 : 0;
        const int o   = tid - OO * bb2;
        const float4* hf = (const float4*)(&hfin[bb2][0]);
        const float4* wp = (const float4*)(fc_w + o * HH);
        float acc = fc_b[o];
#pragma unroll 8
        for (int v = 0; v < HH / 4; ++v) {
            float4 w4 = wp[v];
            float4 h4 = hf[v];
            acc = fmaf(w4.x, h4.x, acc); acc = fmaf(w4.y, h4.y, acc);
            acc = fmaf(w4.z, h4.z, acc); acc = fmaf(w4.w, h4.w, acc);
        }
        out[(size_t)(b0 + bb2) * OO + o] = acc;
    }
}

extern "C" void kernel_launch(void* const* d_in, const int* in_sizes, int n_in,
                              void* d_out, int out_size, void* d_ws, size_t ws_size,
                              hipStream_t stream) {
    const float* x    = (const float*)d_in[0];
    const float* w_ih = (const float*)d_in[1];
    const float* w_hh = (const float*)d_in[2];
    const float* b_ih = (const float*)d_in[3];
    const float* b_hh = (const float*)d_in[4];
    const float* fc_w = (const float*)d_in[5];
    const float* fc_b = (const float*)d_in[6];
    float* out = (float*)d_out;

    gru_kernel<<<BB / 2, 512, 0, stream>>>(x, w_ih, w_hh, b_ih, b_hh, fc_w, fc_b, out);
}

// Round 9
// 884.746 us; speedup vs baseline: 1.0890x; 1.0890x over previous
//
#include <hip/hip_runtime.h>

#define BB 512
#define TT 2048
#define II 8
#define HH 128
#define OO 96

typedef __attribute__((ext_vector_type(8))) short bf16x8;
typedef __attribute__((ext_vector_type(4))) float f32x4;

#define L2E 1.4426950408889634f

__device__ __forceinline__ float fast_rcp(float x) { return __builtin_amdgcn_rcpf(x); }
__device__ __forceinline__ float exp2_fast(float x) {
#if __has_builtin(__builtin_amdgcn_exp2f)
    return __builtin_amdgcn_exp2f(x);
#else
    return __expf(x * 0.6931471805599453f);
#endif
}
__device__ __forceinline__ unsigned short f2bf(float f) {
    unsigned int u = __builtin_bit_cast(unsigned int, f);
    u += 0x7fffu + ((u >> 16) & 1u);   // RNE
    return (unsigned short)(u >> 16);
}
__device__ __forceinline__ float bf2f(unsigned short h) {
    unsigned int u = ((unsigned int)h) << 16;
    return __builtin_bit_cast(float, u);
}
__device__ __forceinline__ float dot8(const float w[8], float4 a, float4 b, float acc) {
    acc = fmaf(w[0], a.x, acc); acc = fmaf(w[1], a.y, acc);
    acc = fmaf(w[2], a.z, acc); acc = fmaf(w[3], a.w, acc);
    acc = fmaf(w[4], b.x, acc); acc = fmaf(w[5], b.y, acc);
    acc = fmaf(w[6], b.z, acc); acc = fmaf(w[7], b.w, acc);
    return acc;
}

// Block = 8 waves (512 thr), 2 batch rows, full T scan, grid=256 (1 block/CU).
// This is the r7 kernel (verified best: 914.6 us) restored verbatim after r8's
// raw-barrier regression, with one codegen-guarantee micro: the first MFMA of
// each gate chain consumes the persistent zero vector zf directly (no
// accumulator-copy movs possible).
//
// Structure ledger (rounds 0-8): 2 waves/SIMD is the unique schedule holding the
// 96-tile/step MFMA floor (466cyc/SIMD) while hiding latency; __syncthreads is
// cheaper than any hand-rolled barrier (r4,r8: raw s_barrier +50-60cyc/step);
// ln<32 write guard avoids doubled LDS write conflicts (r4); zero-init
// accumulators beat gx-folded C-init (r5); 4-deep accumulate chains beat 2x2
// split (r6); role-split r/z sigmoid sharing is the one verified win (r7):
// lanes<32 evaluate r, lanes>=32 evaluate z through the same instruction
// stream; __shfl_xor(.,32) delivers z to the h-update (only lanes<32 need
// valid h). exp2-prescale: r,z weights/biases by -log2e, n by +2log2e -> raw
// v_exp2, no per-gate scaling ops.
// Wave w owns j-block [16w,16w+16). MFMA 16x16x32 bf16, K=128 (h only; x-path
// via fp32 dot8 one iteration ahead, balanced 2 dots per STEP).
// A-row pattern m: plane=((m>>2)&1)*2+(m&1) over {hi0,lo0,hi1,lo1};
// gate = C[0]+C[1] (bf16 hi/lo split compensation).
// LDS: 2 bufs x 4 planes x 320B, double-buffered, 1 barrier per step.
__global__ __launch_bounds__(512, 2) void gru_kernel(
    const float* __restrict__ x,     // [B, T, I]
    const float* __restrict__ w_ih,  // [3H, I]
    const float* __restrict__ w_hh,  // [3H, H]
    const float* __restrict__ b_ih,  // [3H]
    const float* __restrict__ b_hh,  // [3H]
    const float* __restrict__ fc_w,  // [O, H]
    const float* __restrict__ fc_b,  // [O]
    float* __restrict__ out)         // [B, O]
{
    __shared__ __align__(16) char hbuf[2 * 1280];
    __shared__ __align__(16) float hfin[2][HH];

    const int tid = threadIdx.x;
    const int wv  = tid >> 6;
    const int ln  = tid & 63;
    const int col = ln & 15;       // C col = j within tile
    const int g4  = ln >> 4;       // k-subblock of A/B fragment
    const int b   = g4 & 1;        // this lane's batch row
    const int sel = (ln >= 32);    // 0: finalize r-chain; 1: finalize z-chain
    const int p   = ((ln >> 2) & 1) * 2 + (ln & 1);   // A plane for row=ln&15
    const int j   = 16 * wv + col;
    const int b0  = blockIdx.x * 2;

    // ---- B fragments (w_hh -> bf16, weight-stationary, exp2-prescaled) ----
    auto ldfrag_hh = [&](int grow, int ks, float sc) {
        const float* rowp = w_hh + grow * HH + 32 * ks + g4 * 8;
        float4 u = *(const float4*)(rowp);
        float4 v = *(const float4*)(rowp + 4);
        bf16x8 f;
        f[0] = (short)f2bf(sc * u.x); f[1] = (short)f2bf(sc * u.y);
        f[2] = (short)f2bf(sc * u.z); f[3] = (short)f2bf(sc * u.w);
        f[4] = (short)f2bf(sc * v.x); f[5] = (short)f2bf(sc * v.y);
        f[6] = (short)f2bf(sc * v.z); f[7] = (short)f2bf(sc * v.w);
        return f;
    };

    bf16x8 bR[4], bZ[4], bN[4];
#pragma unroll
    for (int ks = 0; ks < 4; ++ks) {
        bR[ks] = ldfrag_hh(j, ks, -L2E);
        bZ[ks] = ldfrag_hh(HH + j, ks, -L2E);
        bN[ks] = ldfrag_hh(2 * HH + j, ks, 2.0f * L2E);
    }

    // ---- w_ih rows for this lane's role (fp32, exp2-prescaled) ----
    const int rz_row = sel ? (HH + j) : j;
    float wrz[8], wn[8];
    {
        const float* rzp = w_ih + rz_row * II;
        const float* r2p = w_ih + (2 * HH + j) * II;
#pragma unroll
        for (int i = 0; i < 8; ++i) {
            wrz[i] = -L2E * rzp[i];
            wn[i]  = (2.0f * L2E) * r2p[i];
        }
    }

    const float bias_rz2 = -L2E * (b_ih[rz_row] + b_hh[rz_row]);
    const float bias_nh2 = (2.0f * L2E) * b_hh[2 * HH + j];  // inside r*(.), added in tail
    const float bias_nx2 = (2.0f * L2E) * b_ih[2 * HH + j];  // outside, in gx dot

    // ---- zero LDS (h=0 both buffers): 2560 B ----
    for (int i = tid; i < 640; i += 512) ((int*)hbuf)[i] = 0;
    __syncthreads();

    const char* abase = hbuf + p * 320 + g4 * 16;
    char* wbase = hbuf + b * 640 + (j << 1);          // + (1-RBUF)*1280 at use
    const float* xp = x + (size_t)(b0 + b) * TT * II;

    float h0 = 0.f;
    const f32x4 zf = {0.f, 0.f, 0.f, 0.f};

    // ---- prologue: gx for t=0,1 (bias folded into dot accumulator) ----
    float grz0, gn0, grz1, gn1;
    {
        float4 xa = *(const float4*)(xp);          float4 xb = *(const float4*)(xp + 4);
        float4 xc = *(const float4*)(xp + II);     float4 xd = *(const float4*)(xp + II + 4);
        grz0 = dot8(wrz, xa, xb, bias_rz2);  gn0 = dot8(wn, xa, xb, bias_nx2);
        grz1 = dot8(wrz, xc, xd, bias_rz2);  gn1 = dot8(wn, xc, xd, bias_nx2);
    }
    float grz0n, gn0n, grz1n, gn1n;

#define MFMA_BF16 __builtin_amdgcn_mfma_f32_16x16x32_bf16

#define STEP(RBUF, GRZ, GXN, DOTS)                                              \
    {                                                                           \
        const char* ab = abase + (RBUF) * 1280;                                 \
        bf16x8 a0 = *(const bf16x8*)(ab);                                       \
        bf16x8 a1 = *(const bf16x8*)(ab + 64);                                  \
        bf16x8 a2 = *(const bf16x8*)(ab + 128);                                 \
        bf16x8 a3 = *(const bf16x8*)(ab + 192);                                 \
        f32x4 aR = MFMA_BF16(a0, bR[0], zf, 0, 0, 0);                           \
        f32x4 aZ = MFMA_BF16(a0, bZ[0], zf, 0, 0, 0);                           \
        f32x4 aN = MFMA_BF16(a0, bN[0], zf, 0, 0, 0);                           \
        aR = MFMA_BF16(a1, bR[1], aR, 0, 0, 0);                                 \
        aZ = MFMA_BF16(a1, bZ[1], aZ, 0, 0, 0);                                 \
        aN = MFMA_BF16(a1, bN[1], aN, 0, 0, 0);                                 \
        aR = MFMA_BF16(a2, bR[2], aR, 0, 0, 0);                                 \
        aZ = MFMA_BF16(a2, bZ[2], aZ, 0, 0, 0);                                 \
        aN = MFMA_BF16(a2, bN[2], aN, 0, 0, 0);                                 \
        aR = MFMA_BF16(a3, bR[3], aR, 0, 0, 0);                                 \
        aZ = MFMA_BF16(a3, bZ[3], aZ, 0, 0, 0);                                 \
        aN = MFMA_BF16(a3, bN[3], aN, 0, 0, 0);                                 \
        DOTS                                                                    \
        float c0 = sel ? aZ[0] : aR[0];                                         \
        float c1 = sel ? aZ[1] : aR[1];                                         \
        float grz = c0 + c1 + (GRZ);                                            \
        float s0v = fast_rcp(1.0f + exp2_fast(grz));  /* r (lo) / z (hi) */     \
        float zz  = __shfl_xor(s0v, 32, 64);          /* z on lo-lanes */       \
        float gn  = aN[0] + aN[1] + bias_nh2;                                   \
        float t0  = fast_rcp(1.0f + exp2_fast(fmaf(s0v, gn, (GXN))));           \
        float n0  = fmaf(-2.0f, t0, 1.0f);                                      \
        h0 = fmaf(zz, h0 - n0, n0);                   /* valid on lo-lanes */   \
        if (ln < 32) {                                                          \
            char* w_ = wbase + (1 - (RBUF)) * 1280;                             \
            unsigned short s0 = f2bf(h0);                                       \
            *(unsigned short*)(w_)       = s0;                                  \
            *(unsigned short*)(w_ + 320) = f2bf(h0 - bf2f(s0));                 \
        }                                                                       \
        __syncthreads();                                                        \
    }

    for (int it = 0; it < TT / 2; ++it) {
        // prefetch x(t+2), x(t+3) -- consumed by DOTS (2 per STEP, balanced)
        int t2 = 2 * it + 2; if (t2 > TT - 1) t2 = TT - 1;
        int t3 = t2 + 1;     if (t3 > TT - 1) t3 = TT - 1;
        float4 pa = *(const float4*)(xp + (size_t)t2 * II);
        float4 pb = *(const float4*)(xp + (size_t)t2 * II + 4);
        float4 pc = *(const float4*)(xp + (size_t)t3 * II);
        float4 pd = *(const float4*)(xp + (size_t)t3 * II + 4);

        STEP(0, grz0, gn0, {                    // even t: read buf0, write buf1
            grz0n = dot8(wrz, pa, pb, bias_rz2);
            gn0n  = dot8(wn,  pa, pb, bias_nx2);
        })
        STEP(1, grz1, gn1, {                    // odd  t: read buf1, write buf0
            grz1n = dot8(wrz, pc, pd, bias_rz2);
            gn1n  = dot8(wn,  pc, pd, bias_nx2);
        })
        grz0 = grz0n; gn0 = gn0n;
        grz1 = grz1n; gn1 = gn1n;
    }
#undef STEP
#undef MFMA_BF16

    // ---- epilogue FC on fp32 h ----
    if (ln < 32) hfin[b][j] = h0;
    __syncthreads();

    if (tid < 2 * OO) {
        const int bb2 = (tid >= OO) ? 1 : 0;
        const int o   = tid - OO * bb2;
        const float4* hf = (const float4*)(&hfin[bb2][0]);
        const float4* wp = (const float4*)(fc_w + o * HH);
        float acc = fc_b[o];
#pragma unroll 8
        for (int v = 0; v < HH / 4; ++v) {
            float4 w4 = wp[v];
            float4 h4 = hf[v];
            acc = fmaf(w4.x, h4.x, acc); acc = fmaf(w4.y, h4.y, acc);
            acc = fmaf(w4.z, h4.z, acc); acc = fmaf(w4.w, h4.w, acc);
        }
        out[(size_t)(b0 + bb2) * OO + o] = acc;
    }
}

extern "C" void kernel_launch(void* const* d_in, const int* in_sizes, int n_in,
                              void* d_out, int out_size, void* d_ws, size_t ws_size,
                              hipStream_t stream) {
    const float* x    = (const float*)d_in[0];
    const float* w_ih = (const float*)d_in[1];
    const float* w_hh = (const float*)d_in[2];
    const float* b_ih = (const float*)d_in[3];
    const float* b_hh = (const float*)d_in[4];
    const float* fc_w = (const float*)d_in[5];
    const float* fc_b = (const float*)d_in[6];
    float* out = (float*)d_out;

    gru_kernel<<<BB / 2, 512, 0, stream>>>(x, w_ih, w_hh, b_ih, b_hh, fc_w, fc_b, out);
}